// Round 3
// baseline (455.677 us; speedup 1.0000x reference)
//
#include <hip/hip_runtime.h>
#include <hip/hip_fp16.h>
#include <math.h>

#define NNODES 100000
#define NEG_SLOPE 0.2f
#define FIN 500
#define KP 512     // padded K
#define HID 128    // heads*hidden
#define NH 4
#define CHUNK 1024

typedef __attribute__((ext_vector_type(8))) short short8v;
typedef __attribute__((ext_vector_type(4))) float f32x4;

__device__ __forceinline__ float lrelu(float x) { return x > 0.f ? x : NEG_SLOPE * x; }

__device__ __forceinline__ unsigned short f32_to_bf16_rn(float f) {
  unsigned u = __float_as_uint(f);
  unsigned r = u + 0x7fffu + ((u >> 16) & 1u);
  return (unsigned short)(r >> 16);
}
__device__ __forceinline__ float bf16_to_f32(unsigned short h) {
  return __uint_as_float(((unsigned)h) << 16);
}

// swizzled LDS offset for [row][k] tile, row stride 32 shorts, 16B slots
__device__ __forceinline__ int lds_off(int row, int slot8) {
  return row * 32 + ((slot8 ^ ((row >> 1) & 3)) << 3);
}

// ---------------- W1 -> transposed bf16 hi/lo [128][512] ----------------
__global__ __launch_bounds__(256) void convert_w1_kernel(const float* __restrict__ W1,
                                                         short* __restrict__ BhT,
                                                         short* __restrict__ BlT) {
  int idx = blockIdx.x * 256 + threadIdx.x;  // 65536
  int n = idx >> 9, k = idx & 511;
  float v = (k < FIN) ? W1[k * HID + n] : 0.f;
  unsigned short hb = f32_to_bf16_rn(v);
  float lo = v - bf16_to_f32(hb);
  BhT[n * KP + k] = (short)hb;
  BlT[n * KP + k] = (short)f32_to_bf16_rn(lo);
}

// ---------------- GEMM1 via split-bf16 MFMA: z1h[M,128] = fp16(A[M,500] @ W1) ----------------
__global__ __launch_bounds__(256) void gemm1_mfma_kernel(const float* __restrict__ A,
                                                         const short* __restrict__ BhT,
                                                         const short* __restrict__ BlT,
                                                         __half* __restrict__ z1h) {
  __shared__ __align__(16) short Ah[128 * 32];
  __shared__ __align__(16) short Al[128 * 32];
  __shared__ __align__(16) short Bh[128 * 32];
  __shared__ __align__(16) short Bl[128 * 32];
  int t = threadIdx.x;
  int bm = blockIdx.x * 128;
  int wid = t >> 6, lane = t & 63;
  int wr = wid >> 1, wc = wid & 1;
  int fr = lane & 15, ko = lane >> 4;

  f32x4 acc[4][4];
#pragma unroll
  for (int i = 0; i < 4; i++)
#pragma unroll
    for (int j = 0; j < 4; j++) acc[i][j] = (f32x4){0.f, 0.f, 0.f, 0.f};

  for (int k0 = 0; k0 < KP; k0 += 32) {
#pragma unroll
    for (int it = 0; it < 2; it++) {
      int s = t + it * 256;
      int row = s >> 2, slot = s & 3;
      int grow = bm + row;
      int kk = k0 + slot * 8;
      float v[8];
      if (grow < NNODES && kk + 7 < FIN) {
        float4 v0 = *(const float4*)&A[(size_t)grow * FIN + kk];
        float4 v1 = *(const float4*)&A[(size_t)grow * FIN + kk + 4];
        v[0] = v0.x; v[1] = v0.y; v[2] = v0.z; v[3] = v0.w;
        v[4] = v1.x; v[5] = v1.y; v[6] = v1.z; v[7] = v1.w;
      } else {
#pragma unroll
        for (int i = 0; i < 8; i++)
          v[i] = (grow < NNODES && kk + i < FIN) ? A[(size_t)grow * FIN + kk + i] : 0.f;
      }
      short8v hv, lv;
#pragma unroll
      for (int i = 0; i < 8; i++) {
        unsigned short hb = f32_to_bf16_rn(v[i]);
        float lo = v[i] - bf16_to_f32(hb);
        hv[i] = (short)hb;
        lv[i] = (short)f32_to_bf16_rn(lo);
      }
      int off = lds_off(row, slot);
      *(short8v*)&Ah[off] = hv;
      *(short8v*)&Al[off] = lv;
    }
#pragma unroll
    for (int it = 0; it < 2; it++) {
      int s = t + it * 256;
      int n = s >> 2, slot = s & 3;
      short8v hv = *(const short8v*)&BhT[n * KP + k0 + slot * 8];
      short8v lv = *(const short8v*)&BlT[n * KP + k0 + slot * 8];
      int off = lds_off(n, slot);
      *(short8v*)&Bh[off] = hv;
      *(short8v*)&Bl[off] = lv;
    }
    __syncthreads();
    short8v af_h[4], af_l[4], bf_h[4], bf_l[4];
#pragma unroll
    for (int mi = 0; mi < 4; mi++) {
      int row = wr * 64 + mi * 16 + fr;
      int off = lds_off(row, ko);
      af_h[mi] = *(short8v*)&Ah[off];
      af_l[mi] = *(short8v*)&Al[off];
    }
#pragma unroll
    for (int ni = 0; ni < 4; ni++) {
      int col = wc * 64 + ni * 16 + fr;
      int off = lds_off(col, ko);
      bf_h[ni] = *(short8v*)&Bh[off];
      bf_l[ni] = *(short8v*)&Bl[off];
    }
#pragma unroll
    for (int mi = 0; mi < 4; mi++)
#pragma unroll
      for (int ni = 0; ni < 4; ni++) {
        acc[mi][ni] = __builtin_amdgcn_mfma_f32_16x16x32_bf16(af_h[mi], bf_h[ni], acc[mi][ni], 0, 0, 0);
        acc[mi][ni] = __builtin_amdgcn_mfma_f32_16x16x32_bf16(af_l[mi], bf_h[ni], acc[mi][ni], 0, 0, 0);
        acc[mi][ni] = __builtin_amdgcn_mfma_f32_16x16x32_bf16(af_h[mi], bf_l[ni], acc[mi][ni], 0, 0, 0);
      }
    __syncthreads();
  }
  // epilogue: C/D layout col=lane&15, row=(lane>>4)*4+reg; store fp16
#pragma unroll
  for (int mi = 0; mi < 4; mi++) {
#pragma unroll
    for (int r = 0; r < 4; r++) {
      int grow = bm + wr * 64 + mi * 16 + ko * 4 + r;
      if (grow < NNODES) {
#pragma unroll
        for (int ni = 0; ni < 4; ni++) {
          int col = wc * 64 + ni * 16 + fr;
          z1h[(size_t)grow * HID + col] = __float2half(acc[mi][ni][r]);
        }
      }
    }
  }
}

// ---------------- el/er for layer 1 (from fp16 z1) ----------------
__global__ __launch_bounds__(128) void attn_lr1_kernel(const __half* __restrict__ z1h,
                                                       const float* __restrict__ al,
                                                       const float* __restrict__ ar,
                                                       float* __restrict__ el,
                                                       float* __restrict__ er) {
  int n = blockIdx.x, t = threadIdx.x;
  float v = __half2float(z1h[(size_t)n * HID + t]);
  float l = v * al[t];
  float r = v * ar[t];
#pragma unroll
  for (int m = 16; m >= 1; m >>= 1) {
    l += __shfl_xor(l, m);
    r += __shfl_xor(r, m);
  }
  if ((t & 31) == 0) {
    el[n * NH + (t >> 5)] = l;
    er[n * NH + (t >> 5)] = r;
  }
}

// ---------------- CSR offsets from sorted dst ----------------
__global__ void csr_offsets_kernel(const int* __restrict__ dst, int E, int* __restrict__ off) {
  int n = blockIdx.x * blockDim.x + threadIdx.x;
  if (n > NNODES) return;
  int lo = 0, hi = E;
  while (lo < hi) {
    int mid = (lo + hi) >> 1;
    if (dst[mid] < n) lo = mid + 1; else hi = mid;
  }
  off[n] = lo;
}

// ---------------- layer-1: single-gather online-softmax + fp16 aggregation ----------------
__global__ __launch_bounds__(128) void gat1_agg_kernel(const __half* __restrict__ z1h,
                                                       const float* __restrict__ el,
                                                       const float* __restrict__ er,
                                                       const int* __restrict__ src,
                                                       const int* __restrict__ off,
                                                       const float* __restrict__ b1,
                                                       float* __restrict__ h1) {
  int n = blockIdx.x, t = threadIdx.x;
  int start = off[n], end = off[n + 1];
  __shared__ __align__(16) float p_sh[CHUNK * 4];
  __shared__ int src_sh[CHUNK];
  __shared__ float redmax[2][4];
  __shared__ float redsum[2][4];
  __shared__ float comb[64 * 2];
  const float4* el4 = reinterpret_cast<const float4*>(el);
  float4 er4 = reinterpret_cast<const float4*>(er)[n];

  int c = t & 63, g = t >> 6;   // column-pair id, edge-parity group
  int head = c >> 4;
  float2 acc = make_float2(0.f, 0.f);
  float m_run[4] = {-INFINITY, -INFINITY, -INFINITY, -INFINITY};
  float d_run[4] = {0.f, 0.f, 0.f, 0.f};

  for (int base = start; base < end; base += CHUNK) {
    int cnt = min(CHUNK, end - base);
    // phase A: gather el once, compute scores into LDS, track chunk max
    float mx[4] = {-INFINITY, -INFINITY, -INFINITY, -INFINITY};
    for (int i = t; i < cnt; i += 128) {
      int sr = src[base + i];
      float4 x = el4[sr];
      float e0 = lrelu(x.x + er4.x);
      float e1 = lrelu(x.y + er4.y);
      float e2 = lrelu(x.z + er4.z);
      float e3 = lrelu(x.w + er4.w);
      src_sh[i] = sr;
      ((float4*)p_sh)[i] = make_float4(e0, e1, e2, e3);
      mx[0] = fmaxf(mx[0], e0); mx[1] = fmaxf(mx[1], e1);
      mx[2] = fmaxf(mx[2], e2); mx[3] = fmaxf(mx[3], e3);
    }
#pragma unroll
    for (int msk = 32; msk >= 1; msk >>= 1)
#pragma unroll
      for (int j = 0; j < 4; j++) mx[j] = fmaxf(mx[j], __shfl_xor(mx[j], msk));
    if ((t & 63) == 0)
#pragma unroll
      for (int j = 0; j < 4; j++) redmax[g][j] = mx[j];
    __syncthreads();
    float m_new[4];
#pragma unroll
    for (int j = 0; j < 4; j++)
      m_new[j] = fmaxf(m_run[j], fmaxf(redmax[0][j], redmax[1][j]));

    // phase B: p = exp(e - m_new) in-place, accumulate chunk denom
    float sm[4] = {0.f, 0.f, 0.f, 0.f};
    for (int i = t; i < cnt; i += 128) {
      float4 e = ((float4*)p_sh)[i];
      float p0 = __expf(e.x - m_new[0]);
      float p1 = __expf(e.y - m_new[1]);
      float p2 = __expf(e.z - m_new[2]);
      float p3 = __expf(e.w - m_new[3]);
      ((float4*)p_sh)[i] = make_float4(p0, p1, p2, p3);
      sm[0] += p0; sm[1] += p1; sm[2] += p2; sm[3] += p3;
    }
#pragma unroll
    for (int msk = 32; msk >= 1; msk >>= 1)
#pragma unroll
      for (int j = 0; j < 4; j++) sm[j] += __shfl_xor(sm[j], msk);
    if ((t & 63) == 0)
#pragma unroll
      for (int j = 0; j < 4; j++) redsum[g][j] = sm[j];
    __syncthreads();
    float scale[4];
#pragma unroll
    for (int j = 0; j < 4; j++) {
      scale[j] = __expf(m_run[j] - m_new[j]);  // exp(-inf)=0 on first chunk
      d_run[j] = d_run[j] * scale[j] + (redsum[0][j] + redsum[1][j]);
      m_run[j] = m_new[j];
    }
    acc.x *= scale[head];
    acc.y *= scale[head];

    // phase C: aggregate z1h (fp16) — 2 edges/iter across groups, unroll 2
    const __half2* z2p = reinterpret_cast<const __half2*>(z1h);
    int i = g;
    for (; i + 2 < cnt; i += 4) {
      float pa = p_sh[i * 4 + head];
      float pb = p_sh[(i + 2) * 4 + head];
      float2 va = __half22float2(z2p[(size_t)src_sh[i] * 64 + c]);
      float2 vb = __half22float2(z2p[(size_t)src_sh[i + 2] * 64 + c]);
      acc.x = fmaf(pa, va.x, acc.x); acc.y = fmaf(pa, va.y, acc.y);
      acc.x = fmaf(pb, vb.x, acc.x); acc.y = fmaf(pb, vb.y, acc.y);
    }
    for (; i < cnt; i += 2) {
      float p = p_sh[i * 4 + head];
      float2 v = __half22float2(z2p[(size_t)src_sh[i] * 64 + c]);
      acc.x = fmaf(p, v.x, acc.x); acc.y = fmaf(p, v.y, acc.y);
    }
    __syncthreads();  // protect p_sh/src_sh/redbufs before next chunk
  }

  // combine the two edge-parity groups, normalize, bias+ELU, store
  if (g == 1) { comb[c * 2] = acc.x; comb[c * 2 + 1] = acc.y; }
  __syncthreads();
  if (g == 0) {
    acc.x += comb[c * 2];
    acc.y += comb[c * 2 + 1];
    float inv = 1.f / fmaxf(d_run[head], 1e-9f);
    float v0 = acc.x * inv + b1[2 * c];
    float v1 = acc.y * inv + b1[2 * c + 1];
    v0 = v0 > 0.f ? v0 : __expf(v0) - 1.f;
    v1 = v1 > 0.f ? v1 : __expf(v1) - 1.f;
    ((float2*)h1)[(size_t)n * 64 + c] = make_float2(v0, v1);
  }
}

// ---------------- layer-2 projection ----------------
__global__ __launch_bounds__(128) void proj2_kernel(const float* __restrict__ h1,
                                                    const float* __restrict__ W2,
                                                    const float* __restrict__ al2,
                                                    const float* __restrict__ ar2,
                                                    float* __restrict__ z2,
                                                    float* __restrict__ el2,
                                                    float* __restrict__ er2) {
  int n = blockIdx.x, t = threadIdx.x;
  float hv = h1[(size_t)n * HID + t];
  float p0 = hv * W2[t * 3 + 0];
  float p1 = hv * W2[t * 3 + 1];
  float p2 = hv * W2[t * 3 + 2];
#pragma unroll
  for (int msk = 32; msk >= 1; msk >>= 1) {
    p0 += __shfl_xor(p0, msk);
    p1 += __shfl_xor(p1, msk);
    p2 += __shfl_xor(p2, msk);
  }
  __shared__ float red[2][3];
  if ((t & 63) == 0) {
    red[t >> 6][0] = p0; red[t >> 6][1] = p1; red[t >> 6][2] = p2;
  }
  __syncthreads();
  if (t == 0) {
    float a = red[0][0] + red[1][0];
    float b = red[0][1] + red[1][1];
    float c = red[0][2] + red[1][2];
    z2[n * 3 + 0] = a; z2[n * 3 + 1] = b; z2[n * 3 + 2] = c;
    el2[n] = a * al2[0] + b * al2[1] + c * al2[2];
    er2[n] = a * ar2[0] + b * ar2[1] + c * ar2[2];
  }
}

// ---------------- layer-2 edge softmax + aggregation ----------------
__global__ __launch_bounds__(64) void gat2_agg_kernel(const float* __restrict__ z2,
                                                      const float* __restrict__ el2,
                                                      const float* __restrict__ er2,
                                                      const int* __restrict__ src,
                                                      const int* __restrict__ off,
                                                      const float* __restrict__ b2,
                                                      float* __restrict__ out) {
  int n = blockIdx.x, lane = threadIdx.x;
  int start = off[n], end = off[n + 1];
  float ern = er2[n];
  float mx = -INFINITY;
  for (int e = start + lane; e < end; e += 64) mx = fmaxf(mx, lrelu(el2[src[e]] + ern));
#pragma unroll
  for (int msk = 32; msk >= 1; msk >>= 1) mx = fmaxf(mx, __shfl_xor(mx, msk));
  float s = 0.f;
  for (int e = start + lane; e < end; e += 64) s += __expf(lrelu(el2[src[e]] + ern) - mx);
#pragma unroll
  for (int msk = 32; msk >= 1; msk >>= 1) s += __shfl_xor(s, msk);
  float inv = 1.f / fmaxf(s, 1e-9f);
  float a0 = 0.f, a1 = 0.f, a2 = 0.f;
  for (int e = start + lane; e < end; e += 64) {
    int sr = src[e];
    float p = __expf(lrelu(el2[sr] + ern) - mx) * inv;
    a0 = fmaf(p, z2[sr * 3 + 0], a0);
    a1 = fmaf(p, z2[sr * 3 + 1], a1);
    a2 = fmaf(p, z2[sr * 3 + 2], a2);
  }
#pragma unroll
  for (int msk = 32; msk >= 1; msk >>= 1) {
    a0 += __shfl_xor(a0, msk);
    a1 += __shfl_xor(a1, msk);
    a2 += __shfl_xor(a2, msk);
  }
  if (lane == 0) {
    out[n * 3 + 0] = a0 + b2[0];
    out[n * 3 + 1] = a1 + b2[1];
    out[n * 3 + 2] = a2 + b2[2];
  }
}

extern "C" void kernel_launch(void* const* d_in, const int* in_sizes, int n_in,
                              void* d_out, int out_size, void* d_ws, size_t ws_size,
                              hipStream_t stream) {
  const float* features = (const float*)d_in[0];
  const int* src = (const int*)d_in[1];
  const int* dst = (const int*)d_in[2];
  const float* W1 = (const float*)d_in[3];
  const float* al1 = (const float*)d_in[4];
  const float* ar1 = (const float*)d_in[5];
  const float* b1 = (const float*)d_in[6];
  const float* W2 = (const float*)d_in[7];
  const float* al2 = (const float*)d_in[8];
  const float* ar2 = (const float*)d_in[9];
  const float* b2 = (const float*)d_in[10];
  float* out = (float*)d_out;
  int E = in_sizes[1];

  char* ws = (char*)d_ws;
  size_t o = 0;
  __half* z1h = (__half*)(ws + o); o += (size_t)NNODES * HID * 2;
  float* h1 = (float*)(ws + o);    o += (size_t)NNODES * HID * 4;
  float* el1 = (float*)(ws + o);   o += (size_t)NNODES * NH * 4;
  float* er1 = (float*)(ws + o);   o += (size_t)NNODES * NH * 4;
  float* z2 = (float*)(ws + o);    o += (size_t)NNODES * 3 * 4;
  float* el2 = (float*)(ws + o);   o += (size_t)NNODES * 4;
  float* er2 = (float*)(ws + o);   o += (size_t)NNODES * 4;
  short* BhT = (short*)(ws + o);   o += (size_t)HID * KP * 2;
  short* BlT = (short*)(ws + o);   o += (size_t)HID * KP * 2;
  int* off = (int*)(ws + o);       o += (size_t)(NNODES + 1) * 4;

  convert_w1_kernel<<<256, 256, 0, stream>>>(W1, BhT, BlT);
  gemm1_mfma_kernel<<<(NNODES + 127) / 128, 256, 0, stream>>>(features, BhT, BlT, z1h);
  attn_lr1_kernel<<<NNODES, 128, 0, stream>>>(z1h, al1, ar1, el1, er1);
  csr_offsets_kernel<<<(NNODES + 1 + 255) / 256, 256, 0, stream>>>(dst, E, off);
  gat1_agg_kernel<<<NNODES, 128, 0, stream>>>(z1h, el1, er1, src, off, b1, h1);
  proj2_kernel<<<NNODES, 128, 0, stream>>>(h1, W2, al2, ar2, z2, el2, er2);
  gat2_agg_kernel<<<NNODES, 64, 0, stream>>>(z2, el2, er2, src, off, b2, out);
}

// Round 4
// 300.962 us; speedup vs baseline: 1.5141x; 1.5141x over previous
//
#include <hip/hip_runtime.h>
#include <hip/hip_fp16.h>
#include <math.h>

#define NNODES 100000
#define NEG_SLOPE 0.2f
#define FIN 500
#define KP 512     // padded K
#define HID 128    // heads*hidden
#define NH 4

typedef __attribute__((ext_vector_type(8))) short short8v;
typedef __attribute__((ext_vector_type(4))) float f32x4;

__device__ __forceinline__ float lrelu(float x) { return x > 0.f ? x : NEG_SLOPE * x; }

__device__ __forceinline__ float sel4(float a0, float a1, float a2, float a3, int h) {
  float r = a0;
  r = (h == 1) ? a1 : r;
  r = (h == 2) ? a2 : r;
  r = (h == 3) ? a3 : r;
  return r;
}

__device__ __forceinline__ unsigned short f32_to_bf16_rn(float f) {
  unsigned u = __float_as_uint(f);
  unsigned r = u + 0x7fffu + ((u >> 16) & 1u);
  return (unsigned short)(r >> 16);
}
__device__ __forceinline__ float bf16_to_f32(unsigned short h) {
  return __uint_as_float(((unsigned)h) << 16);
}

// swizzled LDS offset for [row][k] tile, row stride 32 shorts, 16B slots
__device__ __forceinline__ int lds_off(int row, int slot8) {
  return row * 32 + ((slot8 ^ ((row >> 1) & 3)) << 3);
}

// ---------------- W1 -> transposed bf16 hi/lo [128][512] ----------------
__global__ __launch_bounds__(256) void convert_w1_kernel(const float* __restrict__ W1,
                                                         short* __restrict__ BhT,
                                                         short* __restrict__ BlT) {
  int idx = blockIdx.x * 256 + threadIdx.x;  // 65536
  int n = idx >> 9, k = idx & 511;
  float v = (k < FIN) ? W1[k * HID + n] : 0.f;
  unsigned short hb = f32_to_bf16_rn(v);
  float lo = v - bf16_to_f32(hb);
  BhT[n * KP + k] = (short)hb;
  BlT[n * KP + k] = (short)f32_to_bf16_rn(lo);
}

// ---------------- GEMM1 via split-bf16 MFMA: z1h[M,128] = fp16(A[M,500] @ W1) ----------------
__global__ __launch_bounds__(256) void gemm1_mfma_kernel(const float* __restrict__ A,
                                                         const short* __restrict__ BhT,
                                                         const short* __restrict__ BlT,
                                                         __half* __restrict__ z1h) {
  __shared__ __align__(16) short Ah[128 * 32];
  __shared__ __align__(16) short Al[128 * 32];
  __shared__ __align__(16) short Bh[128 * 32];
  __shared__ __align__(16) short Bl[128 * 32];
  int t = threadIdx.x;
  int bm = blockIdx.x * 128;
  int wid = t >> 6, lane = t & 63;
  int wr = wid >> 1, wc = wid & 1;
  int fr = lane & 15, ko = lane >> 4;

  f32x4 acc[4][4];
#pragma unroll
  for (int i = 0; i < 4; i++)
#pragma unroll
    for (int j = 0; j < 4; j++) acc[i][j] = (f32x4){0.f, 0.f, 0.f, 0.f};

  for (int k0 = 0; k0 < KP; k0 += 32) {
#pragma unroll
    for (int it = 0; it < 2; it++) {
      int s = t + it * 256;
      int row = s >> 2, slot = s & 3;
      int grow = bm + row;
      int kk = k0 + slot * 8;
      float v[8];
      if (grow < NNODES && kk + 7 < FIN) {
        float4 v0 = *(const float4*)&A[(size_t)grow * FIN + kk];
        float4 v1 = *(const float4*)&A[(size_t)grow * FIN + kk + 4];
        v[0] = v0.x; v[1] = v0.y; v[2] = v0.z; v[3] = v0.w;
        v[4] = v1.x; v[5] = v1.y; v[6] = v1.z; v[7] = v1.w;
      } else {
#pragma unroll
        for (int i = 0; i < 8; i++)
          v[i] = (grow < NNODES && kk + i < FIN) ? A[(size_t)grow * FIN + kk + i] : 0.f;
      }
      short8v hv, lv;
#pragma unroll
      for (int i = 0; i < 8; i++) {
        unsigned short hb = f32_to_bf16_rn(v[i]);
        float lo = v[i] - bf16_to_f32(hb);
        hv[i] = (short)hb;
        lv[i] = (short)f32_to_bf16_rn(lo);
      }
      int off = lds_off(row, slot);
      *(short8v*)&Ah[off] = hv;
      *(short8v*)&Al[off] = lv;
    }
#pragma unroll
    for (int it = 0; it < 2; it++) {
      int s = t + it * 256;
      int n = s >> 2, slot = s & 3;
      short8v hv = *(const short8v*)&BhT[n * KP + k0 + slot * 8];
      short8v lv = *(const short8v*)&BlT[n * KP + k0 + slot * 8];
      int off = lds_off(n, slot);
      *(short8v*)&Bh[off] = hv;
      *(short8v*)&Bl[off] = lv;
    }
    __syncthreads();
    short8v af_h[4], af_l[4], bf_h[4], bf_l[4];
#pragma unroll
    for (int mi = 0; mi < 4; mi++) {
      int row = wr * 64 + mi * 16 + fr;
      int off = lds_off(row, ko);
      af_h[mi] = *(short8v*)&Ah[off];
      af_l[mi] = *(short8v*)&Al[off];
    }
#pragma unroll
    for (int ni = 0; ni < 4; ni++) {
      int col = wc * 64 + ni * 16 + fr;
      int off = lds_off(col, ko);
      bf_h[ni] = *(short8v*)&Bh[off];
      bf_l[ni] = *(short8v*)&Bl[off];
    }
#pragma unroll
    for (int mi = 0; mi < 4; mi++)
#pragma unroll
      for (int ni = 0; ni < 4; ni++) {
        acc[mi][ni] = __builtin_amdgcn_mfma_f32_16x16x32_bf16(af_h[mi], bf_h[ni], acc[mi][ni], 0, 0, 0);
        acc[mi][ni] = __builtin_amdgcn_mfma_f32_16x16x32_bf16(af_l[mi], bf_h[ni], acc[mi][ni], 0, 0, 0);
        acc[mi][ni] = __builtin_amdgcn_mfma_f32_16x16x32_bf16(af_h[mi], bf_l[ni], acc[mi][ni], 0, 0, 0);
      }
    __syncthreads();
  }
  // epilogue: C/D layout col=lane&15, row=(lane>>4)*4+reg; store fp16
#pragma unroll
  for (int mi = 0; mi < 4; mi++) {
#pragma unroll
    for (int r = 0; r < 4; r++) {
      int grow = bm + wr * 64 + mi * 16 + ko * 4 + r;
      if (grow < NNODES) {
#pragma unroll
        for (int ni = 0; ni < 4; ni++) {
          int col = wc * 64 + ni * 16 + fr;
          z1h[(size_t)grow * HID + col] = __float2half(acc[mi][ni][r]);
        }
      }
    }
  }
}

// ---------------- el/er for layer 1 (from fp16 z1) ----------------
__global__ __launch_bounds__(128) void attn_lr1_kernel(const __half* __restrict__ z1h,
                                                       const float* __restrict__ al,
                                                       const float* __restrict__ ar,
                                                       float* __restrict__ el,
                                                       float* __restrict__ er) {
  int n = blockIdx.x, t = threadIdx.x;
  float v = __half2float(z1h[(size_t)n * HID + t]);
  float l = v * al[t];
  float r = v * ar[t];
#pragma unroll
  for (int m = 16; m >= 1; m >>= 1) {
    l += __shfl_xor(l, m);
    r += __shfl_xor(r, m);
  }
  if ((t & 31) == 0) {
    el[n * NH + (t >> 5)] = l;
    er[n * NH + (t >> 5)] = r;
  }
}

// ---------------- CSR offsets from sorted dst ----------------
__global__ void csr_offsets_kernel(const int* __restrict__ dst, int E, int* __restrict__ off) {
  int n = blockIdx.x * blockDim.x + threadIdx.x;
  if (n > NNODES) return;
  int lo = 0, hi = E;
  while (lo < hi) {
    int mid = (lo + hi) >> 1;
    if (dst[mid] < n) lo = mid + 1; else hi = mid;
  }
  off[n] = lo;
}

// ---------------- layer-1: wave-per-node online-softmax + fp16 aggregation ----------------
__global__ __launch_bounds__(256) void gat1_agg_kernel(const __half* __restrict__ z1h,
                                                       const float* __restrict__ el,
                                                       const float* __restrict__ er,
                                                       const int* __restrict__ src,
                                                       const int* __restrict__ off,
                                                       const float* __restrict__ b1,
                                                       float* __restrict__ h1) {
  int wid = threadIdx.x >> 6, lane = threadIdx.x & 63;
  int n = blockIdx.x * 4 + wid;
  if (n >= NNODES) return;
  __shared__ float p_sh[4][64 * 4];

  int start = off[n], end = off[n + 1];
  const float4* el4 = reinterpret_cast<const float4*>(el);
  float4 er4 = reinterpret_cast<const float4*>(er)[n];
  const __half2* zp = reinterpret_cast<const __half2*>(z1h);

  int c = lane;            // owns half2 column c -> cols 2c,2c+1
  int head = c >> 4;
  float2 acc = make_float2(0.f, 0.f);
  float m0 = -INFINITY, m1 = -INFINITY, m2 = -INFINITY, m3 = -INFINITY;
  float d0 = 0.f, d1 = 0.f, d2 = 0.f, d3 = 0.f;

  for (int base = start; base < end; base += 64) {
    int cnt = min(64, end - base);
    // lane = edge: gather once, score
    int sr = 0;
    float e0 = -INFINITY, e1 = -INFINITY, e2 = -INFINITY, e3 = -INFINITY;
    if (lane < cnt) {
      sr = src[base + lane];
      float4 x = el4[sr];
      e0 = lrelu(x.x + er4.x);
      e1 = lrelu(x.y + er4.y);
      e2 = lrelu(x.z + er4.z);
      e3 = lrelu(x.w + er4.w);
    }
    // wave max per head
    float x0 = e0, x1 = e1, x2 = e2, x3 = e3;
#pragma unroll
    for (int msk = 32; msk >= 1; msk >>= 1) {
      x0 = fmaxf(x0, __shfl_xor(x0, msk));
      x1 = fmaxf(x1, __shfl_xor(x1, msk));
      x2 = fmaxf(x2, __shfl_xor(x2, msk));
      x3 = fmaxf(x3, __shfl_xor(x3, msk));
    }
    float n0 = fmaxf(m0, x0), n1 = fmaxf(m1, x1), n2 = fmaxf(m2, x2), n3 = fmaxf(m3, x3);
    // p = exp(e - m_new); 0 for idle lanes
    float p0 = 0.f, p1 = 0.f, p2 = 0.f, p3 = 0.f;
    if (lane < cnt) {
      p0 = __expf(e0 - n0); p1 = __expf(e1 - n1);
      p2 = __expf(e2 - n2); p3 = __expf(e3 - n3);
    }
    // wave sum per head
    float s0 = p0, s1 = p1, s2 = p2, s3 = p3;
#pragma unroll
    for (int msk = 32; msk >= 1; msk >>= 1) {
      s0 += __shfl_xor(s0, msk);
      s1 += __shfl_xor(s1, msk);
      s2 += __shfl_xor(s2, msk);
      s3 += __shfl_xor(s3, msk);
    }
    float sc0 = __expf(m0 - n0), sc1 = __expf(m1 - n1);
    float sc2 = __expf(m2 - n2), sc3 = __expf(m3 - n3);
    d0 = d0 * sc0 + s0; d1 = d1 * sc1 + s1;
    d2 = d2 * sc2 + s2; d3 = d3 * sc3 + s3;
    m0 = n0; m1 = n1; m2 = n2; m3 = n3;
    float sch = sel4(sc0, sc1, sc2, sc3, head);
    acc.x *= sch;
    acc.y *= sch;
    // publish p to LDS (per-wave buffer), src via shuffle
    *(float4*)&p_sh[wid][lane * 4] = make_float4(p0, p1, p2, p3);
    __builtin_amdgcn_wave_barrier();
    int i = 0;
    for (; i + 1 < cnt; i += 2) {
      int sa = __shfl(sr, i), sb = __shfl(sr, i + 1);
      float pa = p_sh[wid][i * 4 + head];
      float pb = p_sh[wid][(i + 1) * 4 + head];
      float2 va = __half22float2(zp[(size_t)sa * 64 + c]);
      float2 vb = __half22float2(zp[(size_t)sb * 64 + c]);
      acc.x = fmaf(pa, va.x, acc.x); acc.y = fmaf(pa, va.y, acc.y);
      acc.x = fmaf(pb, vb.x, acc.x); acc.y = fmaf(pb, vb.y, acc.y);
    }
    if (i < cnt) {
      int sa = __shfl(sr, i);
      float pa = p_sh[wid][i * 4 + head];
      float2 va = __half22float2(zp[(size_t)sa * 64 + c]);
      acc.x = fmaf(pa, va.x, acc.x); acc.y = fmaf(pa, va.y, acc.y);
    }
    __builtin_amdgcn_wave_barrier();
  }

  float dh = sel4(d0, d1, d2, d3, head);
  float inv = 1.f / fmaxf(dh, 1e-9f);
  float2 bias = reinterpret_cast<const float2*>(b1)[c];
  float v0 = acc.x * inv + bias.x;
  float v1 = acc.y * inv + bias.y;
  v0 = v0 > 0.f ? v0 : __expf(v0) - 1.f;
  v1 = v1 > 0.f ? v1 : __expf(v1) - 1.f;
  reinterpret_cast<float2*>(h1)[(size_t)n * 64 + c] = make_float2(v0, v1);
}

// ---------------- layer-2 projection: z2el = (z2[0..2], el2); er2 separate ----------------
__global__ __launch_bounds__(128) void proj2_kernel(const float* __restrict__ h1,
                                                    const float* __restrict__ W2,
                                                    const float* __restrict__ al2,
                                                    const float* __restrict__ ar2,
                                                    float4* __restrict__ z2el,
                                                    float* __restrict__ er2) {
  int n = blockIdx.x, t = threadIdx.x;
  float hv = h1[(size_t)n * HID + t];
  float p0 = hv * W2[t * 3 + 0];
  float p1 = hv * W2[t * 3 + 1];
  float p2 = hv * W2[t * 3 + 2];
#pragma unroll
  for (int msk = 32; msk >= 1; msk >>= 1) {
    p0 += __shfl_xor(p0, msk);
    p1 += __shfl_xor(p1, msk);
    p2 += __shfl_xor(p2, msk);
  }
  __shared__ float red[2][3];
  if ((t & 63) == 0) {
    red[t >> 6][0] = p0; red[t >> 6][1] = p1; red[t >> 6][2] = p2;
  }
  __syncthreads();
  if (t == 0) {
    float a = red[0][0] + red[1][0];
    float b = red[0][1] + red[1][1];
    float c = red[0][2] + red[1][2];
    z2el[n] = make_float4(a, b, c, a * al2[0] + b * al2[1] + c * al2[2]);
    er2[n] = a * ar2[0] + b * ar2[1] + c * ar2[2];
  }
}

// ---------------- layer-2: wave-per-node single-pass softmax + aggregation ----------------
__global__ __launch_bounds__(256) void gat2_agg_kernel(const float4* __restrict__ z2el,
                                                       const float* __restrict__ er2,
                                                       const int* __restrict__ src,
                                                       const int* __restrict__ off,
                                                       const float* __restrict__ b2,
                                                       float* __restrict__ out) {
  int wid = threadIdx.x >> 6, lane = threadIdx.x & 63;
  int n = blockIdx.x * 4 + wid;
  if (n >= NNODES) return;
  int start = off[n], end = off[n + 1];
  float ern = er2[n];
  float m_run = -INFINITY, d_run = 0.f;
  float a0 = 0.f, a1 = 0.f, a2 = 0.f;
  for (int base = start; base < end; base += 64) {
    int cnt = min(64, end - base);
    float4 z4 = make_float4(0.f, 0.f, 0.f, 0.f);
    float e = -INFINITY;
    if (lane < cnt) {
      z4 = z2el[src[base + lane]];
      e = lrelu(z4.w + ern);
    }
    float mx = e;
#pragma unroll
    for (int msk = 32; msk >= 1; msk >>= 1) mx = fmaxf(mx, __shfl_xor(mx, msk));
    float m_new = fmaxf(m_run, mx);
    float p = (lane < cnt) ? __expf(e - m_new) : 0.f;
    float sm = p;
#pragma unroll
    for (int msk = 32; msk >= 1; msk >>= 1) sm += __shfl_xor(sm, msk);
    float scale = __expf(m_run - m_new);
    d_run = d_run * scale + sm;
    a0 = a0 * scale + p * z4.x;
    a1 = a1 * scale + p * z4.y;
    a2 = a2 * scale + p * z4.z;
    m_run = m_new;
  }
#pragma unroll
  for (int msk = 32; msk >= 1; msk >>= 1) {
    a0 += __shfl_xor(a0, msk);
    a1 += __shfl_xor(a1, msk);
    a2 += __shfl_xor(a2, msk);
  }
  if (lane == 0) {
    float inv = 1.f / fmaxf(d_run, 1e-9f);
    out[n * 3 + 0] = a0 * inv + b2[0];
    out[n * 3 + 1] = a1 * inv + b2[1];
    out[n * 3 + 2] = a2 * inv + b2[2];
  }
}

extern "C" void kernel_launch(void* const* d_in, const int* in_sizes, int n_in,
                              void* d_out, int out_size, void* d_ws, size_t ws_size,
                              hipStream_t stream) {
  const float* features = (const float*)d_in[0];
  const int* src = (const int*)d_in[1];
  const int* dst = (const int*)d_in[2];
  const float* W1 = (const float*)d_in[3];
  const float* al1 = (const float*)d_in[4];
  const float* ar1 = (const float*)d_in[5];
  const float* b1 = (const float*)d_in[6];
  const float* W2 = (const float*)d_in[7];
  const float* al2 = (const float*)d_in[8];
  const float* ar2 = (const float*)d_in[9];
  const float* b2 = (const float*)d_in[10];
  float* out = (float*)d_out;
  int E = in_sizes[1];

  char* ws = (char*)d_ws;
  size_t o = 0;
  __half* z1h = (__half*)(ws + o); o += (size_t)NNODES * HID * 2;
  float* h1 = (float*)(ws + o);    o += (size_t)NNODES * HID * 4;
  float* el1 = (float*)(ws + o);   o += (size_t)NNODES * NH * 4;
  float* er1 = (float*)(ws + o);   o += (size_t)NNODES * NH * 4;
  float4* z2el = (float4*)(ws + o); o += (size_t)NNODES * 16;
  float* er2 = (float*)(ws + o);   o += (size_t)NNODES * 4;
  short* BhT = (short*)(ws + o);   o += (size_t)HID * KP * 2;
  short* BlT = (short*)(ws + o);   o += (size_t)HID * KP * 2;
  int* off = (int*)(ws + o);       o += (size_t)(NNODES + 1) * 4;

  convert_w1_kernel<<<256, 256, 0, stream>>>(W1, BhT, BlT);
  gemm1_mfma_kernel<<<(NNODES + 127) / 128, 256, 0, stream>>>(features, BhT, BlT, z1h);
  attn_lr1_kernel<<<NNODES, 128, 0, stream>>>(z1h, al1, ar1, el1, er1);
  csr_offsets_kernel<<<(NNODES + 1 + 255) / 256, 256, 0, stream>>>(dst, E, off);
  gat1_agg_kernel<<<(NNODES + 3) / 4, 256, 0, stream>>>(z1h, el1, er1, src, off, b1, h1);
  proj2_kernel<<<NNODES, 128, 0, stream>>>(h1, W2, al2, ar2, z2el, er2);
  gat2_agg_kernel<<<(NNODES + 3) / 4, 256, 0, stream>>>(z2el, er2, src, off, b2, out);
}